// Round 10
// baseline (81.319 us; speedup 1.0000x reference)
//
#include <hip/hip_runtime.h>
#include <hip/hip_bf16.h>
#include <math.h>

typedef __bf16 bf16x8 __attribute__((ext_vector_type(8)));
typedef __bf16 bf16x4 __attribute__((ext_vector_type(4)));
typedef float  f32x4  __attribute__((ext_vector_type(4)));

#define N_ROWS 4096
#define E_DIM  256
#define TWO_N  (2 * N_ROWS)
#define BM 256                        /* rows per block  */
#define BN 128                        /* cols per block  */
#define BK 32                         /* K-tile (one 16x16x32 k-step) */
#define NKT (E_DIM / BK)              /* 8 K-tiles */
#define SQRT_L 3.798282567081813f     /* sqrt(10*log2(e)): folded so acc = sim*10*log2(e) */

__device__ __forceinline__ void gload_lds16(const void* g, void* l) {
    __builtin_amdgcn_global_load_lds(
        (const __attribute__((address_space(1))) void*)g,
        (__attribute__((address_space(3))) void*)l,
        16, 0, 0);
}

// ---------------- prep: normalize + fold sqrt(10*log2e) + bf16 cast ----------------
__global__ __launch_bounds__(256) void prep_kernel(
    const float* __restrict__ tab, const float* __restrict__ ts,
    __hip_bfloat16* __restrict__ zn)
{
    const int tid  = threadIdx.x;
    const int wave = tid >> 6, lane = tid & 63;
    const int row  = blockIdx.x * 4 + wave;

    const float* src = row < N_ROWS ? tab + (size_t)row * E_DIM
                                    : ts + (size_t)(row - N_ROWS) * E_DIM;
    const float4 v = *(const float4*)(src + lane * 4);
    float ss = v.x * v.x + v.y * v.y + v.z * v.z + v.w * v.w;
    #pragma unroll
    for (int m = 32; m >= 1; m >>= 1) ss += __shfl_xor(ss, m);
    const float inv = SQRT_L / fmaxf(sqrtf(ss), 1e-8f);
    bf16x4 o = { (__bf16)(v.x * inv), (__bf16)(v.y * inv),
                 (__bf16)(v.z * inv), (__bf16)(v.w * inv) };
    *(bf16x4*)(zn + (size_t)row * E_DIM + lane * 4) = o;
}

// ---------------- fused sim GEMM: 256x128 tile, counted-vmcnt 3-buffer pipeline ----------------
// grid(32,64): i fast (XCD = i%8, fixed A-set/XCD). BK=32, 8 K-tiles.
// Body kt: vmcnt(3) [tile kt landed; kt+1 stays IN FLIGHT across barrier] ->
// raw s_barrier -> issue stage(kt+2) into buf[(kt+2)%3] (= buf read at kt-1, all
// waves past it) -> 8 ds_read_b128 + 16 MFMA (setprio-wrapped). No vmcnt(0) drain
// in the loop. Swizzle (BK=32, 4 chunks/row): chunk = pos ^ ((row>>1)&3), both sides.
// Epilogue: r9-verified store-partial slots (rowExpP slot 2j+half; cross rowPosP).
__global__ __launch_bounds__(512, 4) void simloss_kernel(
    const __hip_bfloat16* __restrict__ zn,
    const int* __restrict__ labels,
    float* __restrict__ rowExpP,   /* [128][8192] */
    float* __restrict__ rowPosP)   /* [64][8192]  */
{
    const int i = blockIdx.x;      // 0..31 (256-row panel)
    const int j = blockIdx.y;      // 0..63 (128-col panel)
    const int rb = i * BM;
    const int cb = j * BN;

    __shared__ __align__(16) char ldsA[3][BM * BK * 2];  // 3 x 16KB
    __shared__ __align__(16) char ldsB[3][BN * BK * 2];  // 3 x 8KB
    __shared__ int labRow[BM];
    __shared__ int labCol[BN];

    const int tid  = threadIdx.x;
    const int lane = tid & 63;
    const int wave = tid >> 6;           // 0..7
    const int wr = wave >> 1, wc = wave & 1;
    const int l15 = lane & 15, lg = lane >> 4;

    if (tid < BM)           labRow[tid]      = labels[(rb + tid) & (N_ROWS - 1)];
    else if (tid < BM + BN) labCol[tid - BM] = labels[(cb + tid - BM) & (N_ROWS - 1)];

    // stage K-tile kt into buffer b: A 16KB (2 issues) + B 8KB (1 issue) per thread
    auto stage = [&](int b, int kt) {
        #pragma unroll
        for (int it = 0; it < 2; ++it) {
            const int idx = it * 512 + tid;          // 0..1023
            const int row = idx >> 2;                // 0..255
            const int sch = (idx & 3) ^ ((row >> 1) & 3);
            gload_lds16(zn + (size_t)(rb + row) * E_DIM + kt * BK + sch * 8,
                        ldsA[b] + (it * 512 + wave * 64) * 16);
        }
        {
            const int idx = tid;                     // 0..511
            const int row = idx >> 2;                // 0..127
            const int sch = (idx & 3) ^ ((row >> 1) & 3);
            gload_lds16(zn + (size_t)(cb + row) * E_DIM + kt * BK + sch * 8,
                        ldsB[b] + (wave * 64) * 16);
        }
    };

    f32x4 acc[4][4];
    #pragma unroll
    for (int a = 0; a < 4; ++a)
        #pragma unroll
        for (int b = 0; b < 4; ++b) acc[a][b] = (f32x4){0.f, 0.f, 0.f, 0.f};

    stage(0, 0);
    stage(1, 1);

    #pragma unroll
    for (int kt = 0; kt < NKT; ++kt) {
        if (kt < NKT - 1) asm volatile("s_waitcnt vmcnt(3)" ::: "memory");
        else              asm volatile("s_waitcnt vmcnt(0)" ::: "memory");
        __builtin_amdgcn_s_barrier();
        asm volatile("" ::: "memory");

        if (kt + 2 < NKT) stage((kt + 2) % 3, kt + 2);

        const char* bA = ldsA[kt % 3];
        const char* bB = ldsB[kt % 3];
        bf16x8 af[4], bfr[4];
        #pragma unroll
        for (int rf = 0; rf < 4; ++rf) {
            const int r = wr * 64 + rf * 16 + l15;   // 0..255
            af[rf] = *(const bf16x8*)(bA + r * 64 + ((lg ^ ((r >> 1) & 3)) << 4));
        }
        #pragma unroll
        for (int cf = 0; cf < 4; ++cf) {
            const int c = wc * 64 + cf * 16 + l15;   // 0..127
            bfr[cf] = *(const bf16x8*)(bB + c * 64 + ((lg ^ ((c >> 1) & 3)) << 4));
        }
        __builtin_amdgcn_s_setprio(1);
        #pragma unroll
        for (int rf = 0; rf < 4; ++rf)
            #pragma unroll
            for (int cf = 0; cf < 4; ++cf)
                acc[rf][cf] = __builtin_amdgcn_mfma_f32_16x16x32_bf16(af[rf], bfr[cf], acc[rf][cf], 0, 0, 0);
        __builtin_amdgcn_s_setprio(0);
        asm volatile("" ::: "memory");
    }

    // ---- epilogue: row-reduce, LDS-gather (reuse ldsA[0]), coalesced stores ----
    const bool isDiag = (i == (j >> 1));
    const bool cross  = (i < 16) != (j < 32);

    float* shRE = (float*)ldsA[0];     // [2][256]
    float* shRP = shRE + 512;          // [2][256]

    int gcol[4], clab[4];
    #pragma unroll
    for (int cf = 0; cf < 4; ++cf) {
        const int cl = wc * 64 + cf * 16 + l15;
        gcol[cf] = cb + cl;
        clab[cf] = labCol[cl];
    }

    #pragma unroll
    for (int rf = 0; rf < 4; ++rf) {
        #pragma unroll
        for (int jj = 0; jj < 4; ++jj) {
            const int rloc = wr * 64 + rf * 16 + lg * 4 + jj;   // 0..255
            const int grow = rb + rloc;
            const int rlab = labRow[rloc];
            float ep = 0.f, pp = 0.f;
            #pragma unroll
            for (int cf = 0; cf < 4; ++cf) {
                const float s = acc[rf][cf][jj];                // = sim * 10*log2(e)
                float e = __builtin_amdgcn_exp2f(s);
                if (isDiag && grow == gcol[cf]) e = 0.f;
                ep += e;
                if (cross && rlab == clab[cf]) pp += s;
            }
            #pragma unroll
            for (int m = 1; m <= 8; m <<= 1) {
                ep += __shfl_xor(ep, m);
                if (cross) pp += __shfl_xor(pp, m);
            }
            if (l15 == 0) {
                shRE[wc * 256 + rloc] = ep;
                if (cross) shRP[wc * 256 + rloc] = pp;
            }
        }
    }

    __syncthreads();   // full drain OK here (once per block; everything retired)

    const int half = tid >> 8;          // 0/1 -> col-half slot
    const int r = tid & 255;
    rowExpP[(size_t)(2 * j + half) * TWO_N + rb + r] = shRE[tid];
    if (cross) {
        const int jm = (j < 32) ? j : j - 32;
        rowPosP[(size_t)(2 * jm + half) * TWO_N + rb + r] = shRP[tid];
    }
}

// ---------------- finalize stage 1: reduce partials -> per-block double ----------------
__global__ __launch_bounds__(256) void fin1_kernel(
    const float* __restrict__ rowExpP, const float* __restrict__ rowPosP,
    const int* __restrict__ labels, double* __restrict__ partial)
{
    __shared__ int hist[128];
    const int tid = threadIdx.x;
    if (tid < 128) hist[tid] = 0;
    __syncthreads();
    for (int idx = tid; idx < N_ROWS; idx += 256) atomicAdd(&hist[labels[idx]], 1);
    __syncthreads();

    const int r = blockIdx.x * 256 + tid;  // 0..8191 (grid = 32)
    float es = 0.f;
    #pragma unroll 8
    for (int s = 0; s < 128; ++s) es += rowExpP[(size_t)s * TWO_N + r];
    float ps = 0.f;
    #pragma unroll 8
    for (int s = 0; s < 64; ++s) ps += rowPosP[(size_t)s * TWO_N + r];

    const int lab = labels[r & (N_ROWS - 1)];
    // ps is scaled by 10*log2(e); 10*sim_sum = ps * ln(2)
    double g = ((double)ps * 0.6931471805599453 - (double)N_ROWS * log((double)es))
               / (2.0 * (double)hist[lab]);

    #pragma unroll
    for (int m = 32; m >= 1; m >>= 1) g += __shfl_xor(g, m);
    __shared__ double wsum[4];
    const int wave = tid >> 6, lane = tid & 63;
    if (lane == 0) wsum[wave] = g;
    __syncthreads();
    if (tid == 0) partial[blockIdx.x] = wsum[0] + wsum[1] + wsum[2] + wsum[3];
}

// ---------------- finalize stage 2: 32 partials -> scalar ----------------
__global__ void fin2_kernel(const double* __restrict__ partial, float* __restrict__ out) {
    if (threadIdx.x == 0) {
        double tot = 0.0;
        for (int b = 0; b < 32; ++b) tot += partial[b];
        out[0] = (float)(-tot / (double)TWO_N);
    }
}

extern "C" void kernel_launch(void* const* d_in, const int* in_sizes, int n_in,
                              void* d_out, int out_size, void* d_ws, size_t ws_size,
                              hipStream_t stream) {
    const float* tab    = (const float*)d_in[0];
    const float* ts     = (const float*)d_in[1];
    const int*   labels = (const int*)d_in[2];

    char* ws = (char*)d_ws;
    __hip_bfloat16* zn = (__hip_bfloat16*)ws;                        // 4 MB
    const size_t znBytes = (size_t)TWO_N * E_DIM * sizeof(__hip_bfloat16);
    float* rowExpP = (float*)(ws + znBytes);                         // 4 MB [128][8192]
    float* rowPosP = rowExpP + (size_t)128 * TWO_N;                  // 2 MB [64][8192]
    double* partial = (double*)(rowPosP + (size_t)64 * TWO_N);       // 256 B

    prep_kernel<<<TWO_N / 4, 256, 0, stream>>>(tab, ts, zn);

    dim3 grid(32, 64);  // i fast (XCD = i%8), 256x128 tiles
    simloss_kernel<<<grid, 512, 0, stream>>>(zn, labels, rowExpP, rowPosP);

    fin1_kernel<<<32, 256, 0, stream>>>(rowExpP, rowPosP, labels, partial);
    fin2_kernel<<<1, 64, 0, stream>>>(partial, (float*)d_out);
}

// Round 11
// 70.721 us; speedup vs baseline: 1.1499x; 1.1499x over previous
//
#include <hip/hip_runtime.h>
#include <hip/hip_bf16.h>
#include <math.h>

typedef __bf16 bf16x8 __attribute__((ext_vector_type(8)));
typedef __bf16 bf16x4 __attribute__((ext_vector_type(4)));
typedef float  f32x4  __attribute__((ext_vector_type(4)));

#define N_ROWS 4096
#define E_DIM  256
#define TWO_N  (2 * N_ROWS)
#define BM 256                        /* rows per block  */
#define BN 128                        /* cols per block  */
#define BK 64
#define SQRT_L 3.798282567081813f     /* sqrt(10*log2(e)): folded so acc = sim*10*log2(e) */

__device__ __forceinline__ void gload_lds16(const void* g, void* l) {
    __builtin_amdgcn_global_load_lds(
        (const __attribute__((address_space(1))) void*)g,
        (__attribute__((address_space(3))) void*)l,
        16, 0, 0);
}

// ---------------- prep: normalize + fold sqrt(10*log2e) + bf16 cast ----------------
__global__ __launch_bounds__(256) void prep_kernel(
    const float* __restrict__ tab, const float* __restrict__ ts,
    __hip_bfloat16* __restrict__ zn)
{
    const int tid  = threadIdx.x;
    const int wave = tid >> 6, lane = tid & 63;
    const int row  = blockIdx.x * 4 + wave;

    const float* src = row < N_ROWS ? tab + (size_t)row * E_DIM
                                    : ts + (size_t)(row - N_ROWS) * E_DIM;
    const float4 v = *(const float4*)(src + lane * 4);
    float ss = v.x * v.x + v.y * v.y + v.z * v.z + v.w * v.w;
    #pragma unroll
    for (int m = 32; m >= 1; m >>= 1) ss += __shfl_xor(ss, m);
    const float inv = SQRT_L / fmaxf(sqrtf(ss), 1e-8f);
    bf16x4 o = { (__bf16)(v.x * inv), (__bf16)(v.y * inv),
                 (__bf16)(v.z * inv), (__bf16)(v.w * inv) };
    *(bf16x4*)(zn + (size_t)row * E_DIM + lane * 4) = o;
}

// ---------------- fused sim GEMM: r9 main loop + shuffle-free table epilogue ----------------
// grid(32,64): i fast (XCD = i%8, fixed 512KB A-set/XCD), 256x128 tile, BK=64,
// single-buffer staging (r9-proven). acc = sim*10*log2e (scale folded into zn).
// Epilogue v2: lane stores its per-row partial (cf-summed) to LDS table
// [2][256][20] f32; 512 threads sum one (wc,row) slot each via 4x ds_read_b128
// and store coalesced to the unique global slot. No shuffles. Cross-only 2nd pass.
__global__ __launch_bounds__(512, 4) void simloss_kernel(
    const __hip_bfloat16* __restrict__ zn,
    const int* __restrict__ labels,
    float* __restrict__ rowExpP,   /* [128][8192] */
    float* __restrict__ rowPosP)   /* [64][8192]  */
{
    const int i = blockIdx.x;      // 0..31 (256-row panel)
    const int j = blockIdx.y;      // 0..63 (128-col panel)

    const int rb = i * BM;
    const int cb = j * BN;

    __shared__ __align__(16) char ldsS[49152];   // staging A(32K)+B(16K); table overlay 40K
    __shared__ int labRow[BM];
    __shared__ int labCol[BN];

    char* ldsA = ldsS;
    char* ldsB = ldsS + 32768;

    const int tid  = threadIdx.x;
    const int lane = tid & 63;
    const int wave = tid >> 6;           // 0..7
    const int wr = wave >> 1, wc = wave & 1;
    const int l15 = lane & 15, lg = lane >> 4;

    if (tid < BM)           labRow[tid]       = labels[(rb + tid) & (N_ROWS - 1)];
    else if (tid < BM + BN) labCol[tid - BM]  = labels[(cb + tid - BM) & (N_ROWS - 1)];

    f32x4 acc[4][4];
    #pragma unroll
    for (int a = 0; a < 4; ++a)
        #pragma unroll
        for (int b = 0; b < 4; ++b) acc[a][b] = (f32x4){0.f, 0.f, 0.f, 0.f};

    #pragma unroll
    for (int kt = 0; kt < E_DIM / BK; ++kt) {
        #pragma unroll
        for (int it = 0; it < 4; ++it) {
            const int idx = it * 512 + wave * 64 + lane;   // 0..2047
            const int row = idx >> 3;                      // 0..255
            const int sch = (idx & 7) ^ (row & 7);
            gload_lds16(zn + (size_t)(rb + row) * E_DIM + kt * BK + sch * 8,
                        ldsA + (it * 512 + wave * 64) * 16);
        }
        #pragma unroll
        for (int it = 0; it < 2; ++it) {
            const int idx = it * 512 + wave * 64 + lane;   // 0..1023
            const int row = idx >> 3;                      // 0..127
            const int sch = (idx & 7) ^ (row & 7);
            gload_lds16(zn + (size_t)(cb + row) * E_DIM + kt * BK + sch * 8,
                        ldsB + (it * 512 + wave * 64) * 16);
        }
        __syncthreads();

        #pragma unroll
        for (int ks = 0; ks < 2; ++ks) {
            bf16x8 af[4], bfr[4];
            #pragma unroll
            for (int rf = 0; rf < 4; ++rf) {
                const int r = wr * 64 + rf * 16 + l15;     // 0..255
                af[rf] = *(const bf16x8*)(ldsA + r * 128 + (((ks * 4 + lg) ^ (r & 7)) << 4));
            }
            #pragma unroll
            for (int cf = 0; cf < 4; ++cf) {
                const int c = wc * 64 + cf * 16 + l15;     // 0..127
                bfr[cf] = *(const bf16x8*)(ldsB + c * 128 + (((ks * 4 + lg) ^ (c & 7)) << 4));
            }
            #pragma unroll
            for (int rf = 0; rf < 4; ++rf)
                #pragma unroll
                for (int cf = 0; cf < 4; ++cf)
                    acc[rf][cf] = __builtin_amdgcn_mfma_f32_16x16x32_bf16(af[rf], bfr[cf], acc[rf][cf], 0, 0, 0);
        }
        __syncthreads();
    }

    // ---- epilogue v2: per-lane partials (VALU only), LDS table, vector-read reduce ----
    const bool isDiag = (i == (j >> 1));
    const bool cross  = (i < 16) != (j < 32);

    int gcol[4], clab[4];
    #pragma unroll
    for (int cf = 0; cf < 4; ++cf) {
        const int cl = wc * 64 + cf * 16 + l15;
        gcol[cf] = cb + cl;
        clab[cf] = labCol[cl];
    }

    float ep[4][4];
    float ppv[4][4];

    if (cross) {
        #pragma unroll
        for (int rf = 0; rf < 4; ++rf)
            #pragma unroll
            for (int jj = 0; jj < 4; ++jj) {
                const int rloc = wr * 64 + rf * 16 + lg * 4 + jj;
                const int rlab = labRow[rloc];
                float e = 0.f, p = 0.f;
                #pragma unroll
                for (int cf = 0; cf < 4; ++cf) {
                    const float s = acc[rf][cf][jj];        // = sim * 10*log2(e)
                    e += __builtin_amdgcn_exp2f(s);
                    if (rlab == clab[cf]) p += s;
                }
                ep[rf][jj] = e;
                ppv[rf][jj] = p;
            }
    } else {
        #pragma unroll
        for (int rf = 0; rf < 4; ++rf)
            #pragma unroll
            for (int jj = 0; jj < 4; ++jj) {
                const int rloc = wr * 64 + rf * 16 + lg * 4 + jj;
                const int grow = rb + rloc;
                float e = 0.f;
                #pragma unroll
                for (int cf = 0; cf < 4; ++cf) {
                    float x = __builtin_amdgcn_exp2f(acc[rf][cf][jj]);
                    if (isDiag && grow == gcol[cf]) x = 0.f;
                    e += x;
                }
                ep[rf][jj] = e;
            }
    }

    float* tbl = (float*)ldsS;   // [2][256][20] f32 = 40KB (overlaid on staging)

    // pass 1: exp sums
    #pragma unroll
    for (int rf = 0; rf < 4; ++rf)
        #pragma unroll
        for (int jj = 0; jj < 4; ++jj) {
            const int rloc = wr * 64 + rf * 16 + lg * 4 + jj;
            tbl[(wc * 256 + rloc) * 20 + l15] = ep[rf][jj];
        }
    __syncthreads();
    {
        const float* row = tbl + tid * 20;                 // tid = wc*256 + rloc
        f32x4 s0 = *(const f32x4*)(row);
        f32x4 s1 = *(const f32x4*)(row + 4);
        f32x4 s2 = *(const f32x4*)(row + 8);
        f32x4 s3 = *(const f32x4*)(row + 12);
        float es = (s0[0]+s0[1]+s0[2]+s0[3]) + (s1[0]+s1[1]+s1[2]+s1[3])
                 + (s2[0]+s2[1]+s2[2]+s2[3]) + (s3[0]+s3[1]+s3[2]+s3[3]);
        rowExpP[(size_t)(2 * j + (tid >> 8)) * TWO_N + rb + (tid & 255)] = es;
    }

    // pass 2 (cross only): positive sums
    if (cross) {
        __syncthreads();
        #pragma unroll
        for (int rf = 0; rf < 4; ++rf)
            #pragma unroll
            for (int jj = 0; jj < 4; ++jj) {
                const int rloc = wr * 64 + rf * 16 + lg * 4 + jj;
                tbl[(wc * 256 + rloc) * 20 + l15] = ppv[rf][jj];
            }
        __syncthreads();
        {
            const float* row = tbl + tid * 20;
            f32x4 s0 = *(const f32x4*)(row);
            f32x4 s1 = *(const f32x4*)(row + 4);
            f32x4 s2 = *(const f32x4*)(row + 8);
            f32x4 s3 = *(const f32x4*)(row + 12);
            float ps = (s0[0]+s0[1]+s0[2]+s0[3]) + (s1[0]+s1[1]+s1[2]+s1[3])
                     + (s2[0]+s2[1]+s2[2]+s2[3]) + (s3[0]+s3[1]+s3[2]+s3[3]);
            const int jm = (j < 32) ? j : j - 32;
            rowPosP[(size_t)(2 * jm + (tid >> 8)) * TWO_N + rb + (tid & 255)] = ps;
        }
    }
}

// ---------------- finalize stage 1: reduce partials -> per-block double ----------------
__global__ __launch_bounds__(256) void fin1_kernel(
    const float* __restrict__ rowExpP, const float* __restrict__ rowPosP,
    const int* __restrict__ labels, double* __restrict__ partial)
{
    __shared__ int hist[128];
    const int tid = threadIdx.x;
    if (tid < 128) hist[tid] = 0;
    __syncthreads();
    for (int idx = tid; idx < N_ROWS; idx += 256) atomicAdd(&hist[labels[idx]], 1);
    __syncthreads();

    const int r = blockIdx.x * 256 + tid;  // 0..8191 (grid = 32)
    float es = 0.f;
    #pragma unroll 8
    for (int s = 0; s < 128; ++s) es += rowExpP[(size_t)s * TWO_N + r];
    float ps = 0.f;
    #pragma unroll 8
    for (int s = 0; s < 64; ++s) ps += rowPosP[(size_t)s * TWO_N + r];

    const int lab = labels[r & (N_ROWS - 1)];
    // ps is scaled by 10*log2(e); 10*sim_sum = ps * ln(2)
    double g = ((double)ps * 0.6931471805599453 - (double)N_ROWS * log((double)es))
               / (2.0 * (double)hist[lab]);

    #pragma unroll
    for (int m = 32; m >= 1; m >>= 1) g += __shfl_xor(g, m);
    __shared__ double wsum[4];
    const int wave = tid >> 6, lane = tid & 63;
    if (lane == 0) wsum[wave] = g;
    __syncthreads();
    if (tid == 0) partial[blockIdx.x] = wsum[0] + wsum[1] + wsum[2] + wsum[3];
}

// ---------------- finalize stage 2: 32 partials -> scalar ----------------
__global__ void fin2_kernel(const double* __restrict__ partial, float* __restrict__ out) {
    if (threadIdx.x == 0) {
        double tot = 0.0;
        for (int b = 0; b < 32; ++b) tot += partial[b];
        out[0] = (float)(-tot / (double)TWO_N);
    }
}

extern "C" void kernel_launch(void* const* d_in, const int* in_sizes, int n_in,
                              void* d_out, int out_size, void* d_ws, size_t ws_size,
                              hipStream_t stream) {
    const float* tab    = (const float*)d_in[0];
    const float* ts     = (const float*)d_in[1];
    const int*   labels = (const int*)d_in[2];

    char* ws = (char*)d_ws;
    __hip_bfloat16* zn = (__hip_bfloat16*)ws;                        // 4 MB
    const size_t znBytes = (size_t)TWO_N * E_DIM * sizeof(__hip_bfloat16);
    float* rowExpP = (float*)(ws + znBytes);                         // 4 MB [128][8192]
    float* rowPosP = rowExpP + (size_t)128 * TWO_N;                  // 2 MB [64][8192]
    double* partial = (double*)(rowPosP + (size_t)64 * TWO_N);       // 256 B

    prep_kernel<<<TWO_N / 4, 256, 0, stream>>>(tab, ts, zn);

    dim3 grid(32, 64);  // i fast (XCD = i%8), 256x128 tiles
    simloss_kernel<<<grid, 512, 0, stream>>>(zn, labels, rowExpP, rowPosP);

    fin1_kernel<<<32, 256, 0, stream>>>(rowExpP, rowPosP, labels, partial);
    fin2_kernel<<<1, 64, 0, stream>>>(partial, (float*)d_out);
}

// Round 12
// 63.129 us; speedup vs baseline: 1.2881x; 1.1203x over previous
//
#include <hip/hip_runtime.h>
#include <hip/hip_bf16.h>
#include <math.h>

typedef __bf16 bf16x8 __attribute__((ext_vector_type(8)));
typedef __bf16 bf16x4 __attribute__((ext_vector_type(4)));
typedef float  f32x4  __attribute__((ext_vector_type(4)));

#define N_ROWS 4096
#define E_DIM  256
#define TWO_N  (2 * N_ROWS)
#define BM 256                        /* rows per block  */
#define BN 128                        /* cols per block  */
#define BK 64
#define SQRT_L 3.798282567081813f     /* sqrt(10*log2(e)): folded so acc = sim*10*log2(e) */

__device__ __forceinline__ void gload_lds16(const void* g, void* l) {
    __builtin_amdgcn_global_load_lds(
        (const __attribute__((address_space(1))) void*)g,
        (__attribute__((address_space(3))) void*)l,
        16, 0, 0);
}

// ---------------- prep: normalize + fold sqrt(10*log2e) + bf16 cast ----------------
__global__ __launch_bounds__(256) void prep_kernel(
    const float* __restrict__ tab, const float* __restrict__ ts,
    __hip_bfloat16* __restrict__ zn)
{
    const int tid  = threadIdx.x;
    const int wave = tid >> 6, lane = tid & 63;
    const int row  = blockIdx.x * 4 + wave;

    const float* src = row < N_ROWS ? tab + (size_t)row * E_DIM
                                    : ts + (size_t)(row - N_ROWS) * E_DIM;
    const float4 v = *(const float4*)(src + lane * 4);
    float ss = v.x * v.x + v.y * v.y + v.z * v.z + v.w * v.w;
    #pragma unroll
    for (int m = 32; m >= 1; m >>= 1) ss += __shfl_xor(ss, m);
    const float inv = SQRT_L / fmaxf(sqrtf(ss), 1e-8f);
    bf16x4 o = { (__bf16)(v.x * inv), (__bf16)(v.y * inv),
                 (__bf16)(v.z * inv), (__bf16)(v.w * inv) };
    *(bf16x4*)(zn + (size_t)row * E_DIM + lane * 4) = o;
}

// ---------------- fused sim GEMM: r11 main loop + spill-free table epilogue ----------------
// grid(32,64): i fast (XCD = i%8), 256x128 tile, BK=64 single-buffer (r9-proven).
// acc = sim*10*log2e (scale folded into zn).
// Epilogue v3 (spill-free): per-(rf,jj) value stored to LDS table IMMEDIATELY
// (no live ep/ppv arrays -> no scratch); cross pass-2 RECOMPUTES p from acc.
// Table reads use rotated chunk order ((step + tid>>3)&3) -> 2-way banks (free).
__global__ __launch_bounds__(512, 4) void simloss_kernel(
    const __hip_bfloat16* __restrict__ zn,
    const int* __restrict__ labels,
    float* __restrict__ rowExpP,   /* [128][8192] */
    float* __restrict__ rowPosP)   /* [64][8192]  */
{
    const int i = blockIdx.x;      // 0..31 (256-row panel)
    const int j = blockIdx.y;      // 0..63 (128-col panel)

    const int rb = i * BM;
    const int cb = j * BN;

    __shared__ __align__(16) char ldsS[49152];   // staging A(32K)+B(16K); table overlay 40K
    __shared__ int labRow[BM];
    __shared__ int labCol[BN];

    char* ldsA = ldsS;
    char* ldsB = ldsS + 32768;

    const int tid  = threadIdx.x;
    const int lane = tid & 63;
    const int wave = tid >> 6;           // 0..7
    const int wr = wave >> 1, wc = wave & 1;
    const int l15 = lane & 15, lg = lane >> 4;

    if (tid < BM)           labRow[tid]       = labels[(rb + tid) & (N_ROWS - 1)];
    else if (tid < BM + BN) labCol[tid - BM]  = labels[(cb + tid - BM) & (N_ROWS - 1)];

    f32x4 acc[4][4];
    #pragma unroll
    for (int a = 0; a < 4; ++a)
        #pragma unroll
        for (int b = 0; b < 4; ++b) acc[a][b] = (f32x4){0.f, 0.f, 0.f, 0.f};

    #pragma unroll
    for (int kt = 0; kt < E_DIM / BK; ++kt) {
        #pragma unroll
        for (int it = 0; it < 4; ++it) {
            const int idx = it * 512 + wave * 64 + lane;   // 0..2047
            const int row = idx >> 3;                      // 0..255
            const int sch = (idx & 7) ^ (row & 7);
            gload_lds16(zn + (size_t)(rb + row) * E_DIM + kt * BK + sch * 8,
                        ldsA + (it * 512 + wave * 64) * 16);
        }
        #pragma unroll
        for (int it = 0; it < 2; ++it) {
            const int idx = it * 512 + wave * 64 + lane;   // 0..1023
            const int row = idx >> 3;                      // 0..127
            const int sch = (idx & 7) ^ (row & 7);
            gload_lds16(zn + (size_t)(cb + row) * E_DIM + kt * BK + sch * 8,
                        ldsB + (it * 512 + wave * 64) * 16);
        }
        __syncthreads();

        #pragma unroll
        for (int ks = 0; ks < 2; ++ks) {
            bf16x8 af[4], bfr[4];
            #pragma unroll
            for (int rf = 0; rf < 4; ++rf) {
                const int r = wr * 64 + rf * 16 + l15;     // 0..255
                af[rf] = *(const bf16x8*)(ldsA + r * 128 + (((ks * 4 + lg) ^ (r & 7)) << 4));
            }
            #pragma unroll
            for (int cf = 0; cf < 4; ++cf) {
                const int c = wc * 64 + cf * 16 + l15;     // 0..127
                bfr[cf] = *(const bf16x8*)(ldsB + c * 128 + (((ks * 4 + lg) ^ (c & 7)) << 4));
            }
            #pragma unroll
            for (int rf = 0; rf < 4; ++rf)
                #pragma unroll
                for (int cf = 0; cf < 4; ++cf)
                    acc[rf][cf] = __builtin_amdgcn_mfma_f32_16x16x32_bf16(af[rf], bfr[cf], acc[rf][cf], 0, 0, 0);
        }
        __syncthreads();
    }

    // ---- epilogue v3: immediate table stores (no live arrays), rotated reads ----
    const bool isDiag = (i == (j >> 1));
    const bool cross  = (i < 16) != (j < 32);

    int gcol[4], clab[4];
    #pragma unroll
    for (int cf = 0; cf < 4; ++cf) {
        const int cl = wc * 64 + cf * 16 + l15;
        gcol[cf] = cb + cl;
        clab[cf] = labCol[cl];
    }

    float* tbl = (float*)ldsS;   // [2][256][20] f32 = 40KB (overlaid on staging)
    const int rot = (tid >> 3) & 3;   // chunk-order rotation key (2-way banks)

    // pass 1: exp sums -> table immediately
    if (cross) {
        #pragma unroll
        for (int rf = 0; rf < 4; ++rf)
            #pragma unroll
            for (int jj = 0; jj < 4; ++jj) {
                const int rloc = wr * 64 + rf * 16 + lg * 4 + jj;
                float e = 0.f;
                #pragma unroll
                for (int cf = 0; cf < 4; ++cf)
                    e += __builtin_amdgcn_exp2f(acc[rf][cf][jj]);
                tbl[(wc * 256 + rloc) * 20 + l15] = e;
            }
    } else {
        #pragma unroll
        for (int rf = 0; rf < 4; ++rf)
            #pragma unroll
            for (int jj = 0; jj < 4; ++jj) {
                const int rloc = wr * 64 + rf * 16 + lg * 4 + jj;
                const int grow = rb + rloc;
                float e = 0.f;
                #pragma unroll
                for (int cf = 0; cf < 4; ++cf) {
                    float x = __builtin_amdgcn_exp2f(acc[rf][cf][jj]);
                    if (isDiag && grow == gcol[cf]) x = 0.f;
                    e += x;
                }
                tbl[(wc * 256 + rloc) * 20 + l15] = e;
            }
    }
    __syncthreads();
    {
        const float* row = tbl + tid * 20;
        float es = 0.f;
        #pragma unroll
        for (int c = 0; c < 4; ++c) {
            const int ch = (c + rot) & 3;
            f32x4 v = *(const f32x4*)(row + ch * 4);
            es += v[0] + v[1] + v[2] + v[3];
        }
        rowExpP[(size_t)(2 * j + (tid >> 8)) * TWO_N + rb + (tid & 255)] = es;
    }

    // pass 2 (cross only): positives recomputed from acc -> table -> reduce
    if (cross) {
        __syncthreads();
        #pragma unroll
        for (int rf = 0; rf < 4; ++rf)
            #pragma unroll
            for (int jj = 0; jj < 4; ++jj) {
                const int rloc = wr * 64 + rf * 16 + lg * 4 + jj;
                const int rlab = labRow[rloc];
                float p = 0.f;
                #pragma unroll
                for (int cf = 0; cf < 4; ++cf)
                    if (rlab == clab[cf]) p += acc[rf][cf][jj];
                tbl[(wc * 256 + rloc) * 20 + l15] = p;
            }
        __syncthreads();
        {
            const float* row = tbl + tid * 20;
            float ps = 0.f;
            #pragma unroll
            for (int c = 0; c < 4; ++c) {
                const int ch = (c + rot) & 3;
                f32x4 v = *(const f32x4*)(row + ch * 4);
                ps += v[0] + v[1] + v[2] + v[3];
            }
            const int jm = (j < 32) ? j : j - 32;
            rowPosP[(size_t)(2 * jm + (tid >> 8)) * TWO_N + rb + (tid & 255)] = ps;
        }
    }
}

// ---------------- finalize stage 1: reduce partials -> per-block double ----------------
__global__ __launch_bounds__(256) void fin1_kernel(
    const float* __restrict__ rowExpP, const float* __restrict__ rowPosP,
    const int* __restrict__ labels, double* __restrict__ partial)
{
    __shared__ int hist[128];
    const int tid = threadIdx.x;
    if (tid < 128) hist[tid] = 0;
    __syncthreads();
    for (int idx = tid; idx < N_ROWS; idx += 256) atomicAdd(&hist[labels[idx]], 1);
    __syncthreads();

    const int r = blockIdx.x * 256 + tid;  // 0..8191 (grid = 32)
    float es = 0.f;
    #pragma unroll 8
    for (int s = 0; s < 128; ++s) es += rowExpP[(size_t)s * TWO_N + r];
    float ps = 0.f;
    #pragma unroll 8
    for (int s = 0; s < 64; ++s) ps += rowPosP[(size_t)s * TWO_N + r];

    const int lab = labels[r & (N_ROWS - 1)];
    // ps is scaled by 10*log2(e); 10*sim_sum = ps * ln(2)
    double g = ((double)ps * 0.6931471805599453 - (double)N_ROWS * log((double)es))
               / (2.0 * (double)hist[lab]);

    #pragma unroll
    for (int m = 32; m >= 1; m >>= 1) g += __shfl_xor(g, m);
    __shared__ double wsum[4];
    const int wave = tid >> 6, lane = tid & 63;
    if (lane == 0) wsum[wave] = g;
    __syncthreads();
    if (tid == 0) partial[blockIdx.x] = wsum[0] + wsum[1] + wsum[2] + wsum[3];
}

// ---------------- finalize stage 2: 32 partials -> scalar ----------------
__global__ void fin2_kernel(const double* __restrict__ partial, float* __restrict__ out) {
    if (threadIdx.x == 0) {
        double tot = 0.0;
        for (int b = 0; b < 32; ++b) tot += partial[b];
        out[0] = (float)(-tot / (double)TWO_N);
    }
}

extern "C" void kernel_launch(void* const* d_in, const int* in_sizes, int n_in,
                              void* d_out, int out_size, void* d_ws, size_t ws_size,
                              hipStream_t stream) {
    const float* tab    = (const float*)d_in[0];
    const float* ts     = (const float*)d_in[1];
    const int*   labels = (const int*)d_in[2];

    char* ws = (char*)d_ws;
    __hip_bfloat16* zn = (__hip_bfloat16*)ws;                        // 4 MB
    const size_t znBytes = (size_t)TWO_N * E_DIM * sizeof(__hip_bfloat16);
    float* rowExpP = (float*)(ws + znBytes);                         // 4 MB [128][8192]
    float* rowPosP = rowExpP + (size_t)128 * TWO_N;                  // 2 MB [64][8192]
    double* partial = (double*)(rowPosP + (size_t)64 * TWO_N);       // 256 B

    prep_kernel<<<TWO_N / 4, 256, 0, stream>>>(tab, ts, zn);

    dim3 grid(32, 64);  // i fast (XCD = i%8), 256x128 tiles
    simloss_kernel<<<grid, 512, 0, stream>>>(zn, labels, rowExpP, rowPosP);

    fin1_kernel<<<32, 256, 0, stream>>>(rowExpP, rowPosP, labels, partial);
    fin2_kernel<<<1, 64, 0, stream>>>(partial, (float*)d_out);
}

// Round 13
// 57.686 us; speedup vs baseline: 1.4097x; 1.0944x over previous
//
#include <hip/hip_runtime.h>
#include <hip/hip_bf16.h>
#include <math.h>

typedef __bf16 bf16x8 __attribute__((ext_vector_type(8)));
typedef __bf16 bf16x4 __attribute__((ext_vector_type(4)));
typedef float  f32x4  __attribute__((ext_vector_type(4)));

#define N_ROWS 4096
#define E_DIM  256
#define TWO_N  (2 * N_ROWS)
#define BT 128                        /* band tile: 128x128 panels (64 panels)  */
#define BK 64
#define NSLOT 65                      /* row-side d=0..32 -> slot d; col-side d=1..32 -> slot 32+d */
#define SQRT_L 3.798282567081813f     /* sqrt(10*log2(e)): folded so acc = sim*10*log2(e) */

__device__ __forceinline__ void gload_lds16(const void* g, void* l) {
    __builtin_amdgcn_global_load_lds(
        (const __attribute__((address_space(1))) void*)g,
        (__attribute__((address_space(3))) void*)l,
        16, 0, 0);
}

// ---------------- prep: normalize + fold sqrt(10*log2e) + bf16 cast ----------------
__global__ __launch_bounds__(256) void prep_kernel(
    const float* __restrict__ tab, const float* __restrict__ ts,
    __hip_bfloat16* __restrict__ zn)
{
    const int tid  = threadIdx.x;
    const int wave = tid >> 6, lane = tid & 63;
    const int row  = blockIdx.x * 4 + wave;

    const float* src = row < N_ROWS ? tab + (size_t)row * E_DIM
                                    : ts + (size_t)(row - N_ROWS) * E_DIM;
    const float4 v = *(const float4*)(src + lane * 4);
    float ss = v.x * v.x + v.y * v.y + v.z * v.z + v.w * v.w;
    #pragma unroll
    for (int m = 32; m >= 1; m >>= 1) ss += __shfl_xor(ss, m);
    const float inv = SQRT_L / fmaxf(sqrtf(ss), 1e-8f);
    bf16x4 o = { (__bf16)(v.x * inv), (__bf16)(v.y * inv),
                 (__bf16)(v.z * inv), (__bf16)(v.w * inv) };
    *(bf16x4*)(zn + (size_t)row * E_DIM + lane * 4) = o;
}

// ---------------- band-symmetric fused sim GEMM ----------------
// grid(64,33): i = blockIdx.x (fast; XCD = i%8 -> fixed 512KB A-set), d = blockIdx.y.
// Tile (i, j=(i+d)&63): each unordered panel pair exactly once (d=32: i<32 only).
// Each off-diag tile emits BOTH row-sums (rows of panel i, slot d) and col-sums
// (rows of panel j, slot 32+d) -> GEMM, LDS and exp work all ~halve vs full grid.
// 128x128 tile, 4 waves (r3-proven main loop), table epilogue (r12-proven pattern),
// store-only unique slots, zero-fill for non-cross pos and d=32 mirror slots.
__global__ __launch_bounds__(256, 4) void simloss_kernel(
    const __hip_bfloat16* __restrict__ zn,
    const int* __restrict__ labels,
    float* __restrict__ rowExpP,   /* [65][8192] */
    float* __restrict__ rowPosP)   /* [65][8192] */
{
    const int i = blockIdx.x;          // 0..63 row panel
    const int d = blockIdx.y;          // 0..32 band
    if (d == 32 && i >= 32) return;    // half-band: pair {i,i+32} once
    const int j = (i + d) & 63;        // col panel

    const int rb = i * BT;
    const int cb = j * BT;

    __shared__ __align__(16) char ldsS[32768];   // staging A(16K)+B(16K); tables overlay
    __shared__ int labRow[BT];
    __shared__ int labCol[BT];

    char* ldsA = ldsS;
    char* ldsB = ldsS + 16384;

    const int tid  = threadIdx.x;
    const int lane = tid & 63;
    const int wave = tid >> 6;           // 0..3
    const int wr = wave >> 1, wc = wave & 1;
    const int l15 = lane & 15, lg = lane >> 4;

    if (tid < BT)      labRow[tid]      = labels[(rb + tid) & (N_ROWS - 1)];
    else               labCol[tid - BT] = labels[(cb + tid - BT) & (N_ROWS - 1)];

    f32x4 acc[4][4];
    #pragma unroll
    for (int a = 0; a < 4; ++a)
        #pragma unroll
        for (int b = 0; b < 4; ++b) acc[a][b] = (f32x4){0.f, 0.f, 0.f, 0.f};

    #pragma unroll
    for (int kt = 0; kt < E_DIM / BK; ++kt) {
        // stage 16KB/matrix (1024 chunks / 256 thr = 4 its): linear LDS dest,
        // pre-swizzled global source chunk (r3-proven)
        #pragma unroll
        for (int it = 0; it < 4; ++it) {
            const int idx = it * 256 + wave * 64 + lane;  // 16B chunk id 0..1023
            const int row = idx >> 3;                     // 0..127
            const int sch = (idx & 7) ^ (row & 7);
            gload_lds16(zn + (size_t)(rb + row) * E_DIM + kt * BK + sch * 8,
                        ldsA + (it * 256 + wave * 64) * 16);
            gload_lds16(zn + (size_t)(cb + row) * E_DIM + kt * BK + sch * 8,
                        ldsB + (it * 256 + wave * 64) * 16);
        }
        __syncthreads();

        #pragma unroll
        for (int ks = 0; ks < 2; ++ks) {
            bf16x8 af[4], bfr[4];
            #pragma unroll
            for (int rf = 0; rf < 4; ++rf) {
                const int r = wr * 64 + rf * 16 + l15;
                af[rf] = *(const bf16x8*)(ldsA + r * 128 + (((ks * 4 + lg) ^ (r & 7)) << 4));
            }
            #pragma unroll
            for (int cf = 0; cf < 4; ++cf) {
                const int c = wc * 64 + cf * 16 + l15;
                bfr[cf] = *(const bf16x8*)(ldsB + c * 128 + (((ks * 4 + lg) ^ (c & 7)) << 4));
            }
            #pragma unroll
            for (int rf = 0; rf < 4; ++rf)
                #pragma unroll
                for (int cf = 0; cf < 4; ++cf)
                    acc[rf][cf] = __builtin_amdgcn_mfma_f32_16x16x32_bf16(af[rf], bfr[cf], acc[rf][cf], 0, 0, 0);
        }
        __syncthreads();
    }

    // ---- epilogue: one sweep -> row table + col regs; reduce; pos pass ----
    const bool isDiag = (d == 0);
    const bool cross  = (i < 32) != (j < 32);

    float* tblRow = (float*)ldsS;            // [128][44] f32 = 22.5KB (overlay)
    float* tblCol = (float*)(ldsS + 22528);  // [128][12] f32 = 6KB

    int cl[4], clab[4];
    #pragma unroll
    for (int cf = 0; cf < 4; ++cf) {
        cl[cf]   = wc * 64 + cf * 16 + l15;
        clab[cf] = labCol[cl[cf]];
    }

    float colE[4] = {0.f, 0.f, 0.f, 0.f};
    float colP[4] = {0.f, 0.f, 0.f, 0.f};

    // sweep 1: exp once per element; row partial -> table, col partial -> regs;
    // also accumulate col pos partial (cross) in regs for later.
    #pragma unroll
    for (int rf = 0; rf < 4; ++rf) {
        #pragma unroll
        for (int jj = 0; jj < 4; ++jj) {
            const int rloc = wr * 64 + rf * 16 + lg * 4 + jj;
            const int rlab = labRow[rloc];
            float rowE = 0.f;
            #pragma unroll
            for (int cf = 0; cf < 4; ++cf) {
                const float s = acc[rf][cf][jj];         // = sim * 10*log2(e)
                float e = __builtin_amdgcn_exp2f(s);
                if (isDiag && rloc == cl[cf]) e = 0.f;
                rowE += e;
                colE[cf] += e;
                if (cross && rlab == clab[cf]) colP[cf] += s;
            }
            tblRow[rloc * 44 + wc * 16 + l15] = rowE;
        }
    }
    // col-exp table (8 contributors per col: wr x lg)
    #pragma unroll
    for (int cf = 0; cf < 4; ++cf)
        tblCol[cl[cf] * 12 + wr * 4 + lg] = colE[cf];

    __syncthreads();

    if (tid < 128) {
        // row-exp reduce (32 contributors, rotated 8x b128)
        const float* rp = tblRow + tid * 44;
        const int rot = (tid >> 3) & 7;
        float es = 0.f;
        #pragma unroll
        for (int c0 = 0; c0 < 8; ++c0) {
            const int ch = (c0 + rot) & 7;
            f32x4 v = *(const f32x4*)(rp + ch * 4);
            es += v[0] + v[1] + v[2] + v[3];
        }
        rowExpP[(size_t)d * TWO_N + rb + tid] = es;

        if (d > 0) {
            // col-exp reduce (8 contributors)
            const float* cp = tblCol + tid * 12;
            f32x4 a = *(const f32x4*)(cp);
            f32x4 b = *(const f32x4*)(cp + 4);
            const float ec = a[0]+a[1]+a[2]+a[3] + b[0]+b[1]+b[2]+b[3];
            rowExpP[(size_t)(32 + d) * TWO_N + cb + tid] = ec;
        }
    }

    // ---- pos slots ----
    if (cross) {
        __syncthreads();
        #pragma unroll
        for (int rf = 0; rf < 4; ++rf) {
            #pragma unroll
            for (int jj = 0; jj < 4; ++jj) {
                const int rloc = wr * 64 + rf * 16 + lg * 4 + jj;
                const int rlab = labRow[rloc];
                float rowP = 0.f;
                #pragma unroll
                for (int cf = 0; cf < 4; ++cf)
                    if (rlab == clab[cf]) rowP += acc[rf][cf][jj];
                tblRow[rloc * 44 + wc * 16 + l15] = rowP;
            }
        }
        #pragma unroll
        for (int cf = 0; cf < 4; ++cf)
            tblCol[cl[cf] * 12 + wr * 4 + lg] = colP[cf];
        __syncthreads();
        if (tid < 128) {
            const float* rp = tblRow + tid * 44;
            const int rot = (tid >> 3) & 7;
            float ps = 0.f;
            #pragma unroll
            for (int c0 = 0; c0 < 8; ++c0) {
                const int ch = (c0 + rot) & 7;
                f32x4 v = *(const f32x4*)(rp + ch * 4);
                ps += v[0] + v[1] + v[2] + v[3];
            }
            rowPosP[(size_t)d * TWO_N + rb + tid] = ps;
            if (d > 0) {
                const float* cp = tblCol + tid * 12;
                f32x4 a = *(const f32x4*)(cp);
                f32x4 b = *(const f32x4*)(cp + 4);
                rowPosP[(size_t)(32 + d) * TWO_N + cb + tid] =
                    a[0]+a[1]+a[2]+a[3] + b[0]+b[1]+b[2]+b[3];
            }
        }
    } else {
        if (tid < 128) {
            rowPosP[(size_t)d * TWO_N + rb + tid] = 0.f;
            if (d > 0) rowPosP[(size_t)(32 + d) * TWO_N + cb + tid] = 0.f;
        }
    }

    // ---- d=32 mirror slots (tiles (j, j+32) for j>=32 are not dispatched) ----
    if (d == 32 && tid < 128) {
        rowExpP[(size_t)64 * TWO_N + rb + tid] = 0.f;   // panel i col-slot
        rowExpP[(size_t)32 * TWO_N + cb + tid] = 0.f;   // panel j row-slot
        rowPosP[(size_t)64 * TWO_N + rb + tid] = 0.f;
        rowPosP[(size_t)32 * TWO_N + cb + tid] = 0.f;
    }
}

// ---------------- finalize stage 1: reduce partials -> per-block double ----------------
__global__ __launch_bounds__(256) void fin1_kernel(
    const float* __restrict__ rowExpP, const float* __restrict__ rowPosP,
    const int* __restrict__ labels, double* __restrict__ partial)
{
    __shared__ int hist[128];
    const int tid = threadIdx.x;
    if (tid < 128) hist[tid] = 0;
    __syncthreads();
    for (int idx = tid; idx < N_ROWS; idx += 256) atomicAdd(&hist[labels[idx]], 1);
    __syncthreads();

    const int r = blockIdx.x * 256 + tid;  // 0..8191 (grid = 32)
    float es = 0.f;
    #pragma unroll 5
    for (int s = 0; s < NSLOT; ++s) es += rowExpP[(size_t)s * TWO_N + r];
    float ps = 0.f;
    #pragma unroll 5
    for (int s = 0; s < NSLOT; ++s) ps += rowPosP[(size_t)s * TWO_N + r];

    const int lab = labels[r & (N_ROWS - 1)];
    // ps is scaled by 10*log2(e); 10*sim_sum = ps * ln(2)
    double g = ((double)ps * 0.6931471805599453 - (double)N_ROWS * log((double)es))
               / (2.0 * (double)hist[lab]);

    #pragma unroll
    for (int m = 32; m >= 1; m >>= 1) g += __shfl_xor(g, m);
    __shared__ double wsum[4];
    const int wave = tid >> 6, lane = tid & 63;
    if (lane == 0) wsum[wave] = g;
    __syncthreads();
    if (tid == 0) partial[blockIdx.x] = wsum[0] + wsum[1] + wsum[2] + wsum[3];
}

// ---------------- finalize stage 2: 32 partials -> scalar ----------------
__global__ void fin2_kernel(const double* __restrict__ partial, float* __restrict__ out) {
    if (threadIdx.x == 0) {
        double tot = 0.0;
        for (int b = 0; b < 32; ++b) tot += partial[b];
        out[0] = (float)(-tot / (double)TWO_N);
    }
}

extern "C" void kernel_launch(void* const* d_in, const int* in_sizes, int n_in,
                              void* d_out, int out_size, void* d_ws, size_t ws_size,
                              hipStream_t stream) {
    const float* tab    = (const float*)d_in[0];
    const float* ts     = (const float*)d_in[1];
    const int*   labels = (const int*)d_in[2];

    char* ws = (char*)d_ws;
    __hip_bfloat16* zn = (__hip_bfloat16*)ws;                        // 4 MB
    const size_t znBytes = (size_t)TWO_N * E_DIM * sizeof(__hip_bfloat16);
    float* rowExpP = (float*)(ws + znBytes);                         // 2.13 MB [65][8192]
    float* rowPosP = rowExpP + (size_t)NSLOT * TWO_N;                // 2.13 MB [65][8192]
    double* partial = (double*)(rowPosP + (size_t)NSLOT * TWO_N);    // 256 B

    prep_kernel<<<TWO_N / 4, 256, 0, stream>>>(tab, ts, zn);

    dim3 grid(64, 33);  // i fast (XCD = i%8, fixed A-set); d slow (fixed B-class/band)
    simloss_kernel<<<grid, 256, 0, stream>>>(zn, labels, rowExpP, rowPosP);

    fin1_kernel<<<32, 256, 0, stream>>>(rowExpP, rowPosP, labels, partial);
    fin2_kernel<<<1, 64, 0, stream>>>(partial, (float*)d_out);
}